// Round 9
// baseline (528.865 us; speedup 1.0000x reference)
//
#include <hip/hip_runtime.h>
#include <hip/hip_bf16.h>

typedef __bf16 bf16_t;
typedef __attribute__((ext_vector_type(8))) __bf16 bf16x8;
typedef __attribute__((ext_vector_type(4))) float f32x4;

#define S_DIM 4096
#define D_DIM 2048

__device__ __forceinline__ unsigned short f2bf(float f) {
  unsigned int u = __float_as_uint(f);
  u += 0x7fff + ((u >> 16) & 1);   // round-to-nearest-even
  return (unsigned short)(u >> 16);
}
__device__ __forceinline__ float bf2f(unsigned short h) {
  return __uint_as_float(((unsigned int)h) << 16);
}

// async global->LDS, 16B per lane. LDS dest must be wave-uniform base + lane*16.
__device__ __forceinline__ void async16(const void* g, void* l) {
  __builtin_amdgcn_global_load_lds(
      (const __attribute__((address_space(1))) void*)g,
      (__attribute__((address_space(3))) void*)l, 16, 0, 0);
}

// T1 XCD swizzle: block with original id computes tile swz. Bijective when
// n % 8 == 0 (qkv 1536, sc 528, av 512 all qualify). Groups n/8 consecutive
// tiles per XCD so shared row-panels stay L2-resident.
__device__ __forceinline__ int xcd_swz(int id, int n) {
  const int cpx = n >> 3;
  return (id & 7) * cpx + (id >> 3);
}

// ---------------------------------------------------------------------------
// JOURNAL (rounds 0-8):
//  - R1 DBUF explicit double-buffer: REGRESSED (m99/m100 reproduced).
//  - R2 TM=128 2-barrier everywhere: 427us. qkv 108us/MfmaUtil 42% = 954 TF,
//    at the m97-structure reference band. BANKED CONFIG.
//  - R3/R6/R7 deep-pipelined (T2-T5) ports: ALL REGRESSED. Root causes:
//    bad ds_read:MFMA ratio (R3), sched_barrier+tiny phases (R6), grid
//    quantization at 1 blk/CU + no TLP fallback for vmcnt stalls (R7).
//  - R8 launch-merge (k_prep): NEUTRAL -> launch gaps are small (graph);
//    remaining time is inside dispatches. qkv FETCH 102MB vs 40MB ideal =
//    2.5x HBM over-fetch -> cross-XCD panel re-reads.
//  - R9: T1 XCD swizzle (all GEMMs) + launch_bounds(256,5) (5 blk/CU,
//    LDS 160KB exact) to shorten/hide the barrier drain.
// ---------------------------------------------------------------------------
// k_prep: dtype probe (per-block, no cross-block dep), x->bf16, W->bf16,
// rowsum zero, flag publish.
__global__ void k_prep(const void* __restrict__ x, const void* __restrict__ w0,
                       const void* __restrict__ w1, const void* __restrict__ w2,
                       unsigned short* __restrict__ xb,
                       unsigned short* __restrict__ wqkv,
                       int* __restrict__ flag, float* __restrict__ rowsum) {
  const int gid = blockIdx.x * 256 + threadIdx.x;
  __shared__ int cnt;
  if (threadIdx.x == 0) cnt = 0;
  __syncthreads();
  const unsigned int e = (((const unsigned int*)x)[threadIdx.x] >> 7) & 0xffu;
  if (e >= 100 && e <= 140) atomicAdd(&cnt, 1);
  __syncthreads();
  const bool isbf = (cnt > 128);
  if (gid == 0) *flag = isbf ? 1 : 0;
  if (gid < S_DIM) rowsum[gid] = 0.f;

  const int NX4 = S_DIM * D_DIM / 4;   // 2,097,152
  if (gid < NX4) {
    if (isbf) {
      ((uint2*)xb)[gid] = ((const uint2*)x)[gid];
    } else {
      float4 f = ((const float4*)x)[gid];
      ushort4 u;
      u.x = f2bf(f.x); u.y = f2bf(f.y); u.z = f2bf(f.z); u.w = f2bf(f.w);
      ((ushort4*)xb)[gid] = u;
    }
  } else {
    const int i = gid - NX4;           // 0 .. 3*1048576-1
    const int which = i >> 20;
    const int off = i & 0xFFFFF;
    const void* src = (which == 0) ? w0 : ((which == 1) ? w1 : w2);
    if (isbf) {
      ((uint2*)wqkv)[i] = ((const uint2*)src)[off];
    } else {
      float4 f = ((const float4*)src)[off];
      ushort4 u;
      u.x = f2bf(f.x); u.y = f2bf(f.y); u.z = f2bf(f.z); u.w = f2bf(f.w);
      ((ushort4*)wqkv)[i] = u;
    }
  }
}

// ===========================================================================
// m97-lite 2-barrier GEMM, 128x128 tile, 256 thr, waves 2x2, BK=64 as two
// BK=32 sub-tiles, 32KB LDS. R9: XCD swizzle + 5 blk/CU.
__global__ __launch_bounds__(256, 5)
void k_gemm_qkv(const bf16_t* __restrict__ A, const bf16_t* __restrict__ B,
                unsigned short* __restrict__ C, int ldA, int ldB, int ldC, int K) {
  const int nbx = gridDim.x;
  const int tile = xcd_swz(blockIdx.y * nbx + blockIdx.x, nbx * gridDim.y);
  const int bm = tile / nbx, bn = tile % nbx;
  const int rowBase = bm * 128;

  __shared__ alignas(16) bf16_t As0[128 * 32];
  __shared__ alignas(16) bf16_t As1[128 * 32];
  __shared__ alignas(16) bf16_t Bs0[128 * 32];
  __shared__ alignas(16) bf16_t Bs1[128 * 32];

  const int tid = threadIdx.x;
  const int lane = tid & 63, wave = tid >> 6;
  const int quad = lane >> 4, l16 = lane & 15;
  const int wm = (wave >> 1) * 64;
  const int wn = (wave & 1) * 64;
  const int sr = tid >> 2;
  const int sc = (tid & 3) * 8;

  f32x4 acc[4][4] = {};

  const unsigned aOff = (unsigned)(rowBase + sr) * (unsigned)ldA + sc;
  const unsigned bOff = (unsigned)(bn * 128 + sr) * (unsigned)ldB + sc;
  const unsigned aOff2 = aOff + 64u * (unsigned)ldA;
  const unsigned bOff2 = bOff + 64u * (unsigned)ldB;
  const unsigned lOff = sr * 32 + sc;

  for (int k0 = 0; k0 < K; k0 += 64) {
    async16(A + (aOff + k0), &As0[lOff]);
    async16(A + (aOff + k0 + 32), &As1[lOff]);
    async16(A + (aOff2 + k0), &As0[lOff + 64 * 32]);
    async16(A + (aOff2 + k0 + 32), &As1[lOff + 64 * 32]);
    async16(B + (bOff + k0), &Bs0[lOff]);
    async16(B + (bOff2 + k0), &Bs0[lOff + 64 * 32]);
    async16(B + (bOff + k0 + 32), &Bs1[lOff]);
    async16(B + (bOff2 + k0 + 32), &Bs1[lOff + 64 * 32]);
    __syncthreads();

    bf16x8 b0[4], b1[4];
#pragma unroll
    for (int j = 0; j < 4; ++j) {
      b0[j] = *(const bf16x8*)&Bs0[(wn + j * 16 + l16) * 32 + quad * 8];
      b1[j] = *(const bf16x8*)&Bs1[(wn + j * 16 + l16) * 32 + quad * 8];
    }
#pragma unroll
    for (int i = 0; i < 4; ++i) {
      const bf16x8 a0 = *(const bf16x8*)&As0[(wm + i * 16 + l16) * 32 + quad * 8];
      const bf16x8 a1 = *(const bf16x8*)&As1[(wm + i * 16 + l16) * 32 + quad * 8];
#pragma unroll
      for (int j = 0; j < 4; ++j) {
        acc[i][j] = __builtin_amdgcn_mfma_f32_16x16x32_bf16(a0, b0[j], acc[i][j], 0, 0, 0);
        acc[i][j] = __builtin_amdgcn_mfma_f32_16x16x32_bf16(a1, b1[j], acc[i][j], 0, 0, 0);
      }
    }
    __syncthreads();
  }

#pragma unroll
  for (int i = 0; i < 4; ++i) {
    const int gr0 = rowBase + wm + i * 16 + quad * 4;
#pragma unroll
    for (int j = 0; j < 4; ++j) {
      const int gc = bn * 128 + wn + j * 16 + l16;
#pragma unroll
      for (int r = 0; r < 4; ++r)
        C[(size_t)(gr0 + r) * ldC + gc] = f2bf(acc[i][j][r]);
    }
  }
}

// ===========================================================================
// R2 generic 2-barrier body for sc/av (banked config) + R9 XCD swizzle.
// OUT_MODE: 2 = /rowsum then flag?bf16:f32 (av -> d_out)
//           3 = softmax-fused scores: exp*mask write + rowsum atomics
// CAUSAL:   1 = triangle 1-D grid over 128x128 tiles (528 blocks)
//           2 = causal-K truncation kEnd=(bm+1)*128 + balanced bm remap
template<int OUT_MODE, int CAUSAL>
__device__ __forceinline__ void gemm_body(
    const bf16_t* __restrict__ A, const bf16_t* __restrict__ B,
    void* __restrict__ C, int ldA, int ldB, int ldC, int K,
    float scale, const int* __restrict__ flag,
    const void* __restrict__ mask, float* __restrict__ rowsum) {
  int bm, bn;
  if (CAUSAL == 1) {
    const int t = xcd_swz(blockIdx.x, 528);
    int u = (int)((sqrtf(8.0f * (float)t + 1.0f) - 1.0f) * 0.5f);
    while (((u + 1) * (u + 2)) / 2 <= t) ++u;
    while ((u * (u + 1)) / 2 > t) --u;
    bm = u;
    bn = t - (u * (u + 1)) / 2;
  } else {
    const int s = xcd_swz(blockIdx.y * gridDim.x + blockIdx.x,
                          gridDim.x * gridDim.y);
    const int gy = s / gridDim.x;
    bm = (gy < 16) ? gy : (47 - gy);
    bn = s % gridDim.x;
  }
  const int rowBase = bm * 128;

  __shared__ alignas(16) bf16_t As0[128 * 32];
  __shared__ alignas(16) bf16_t As1[128 * 32];
  __shared__ alignas(16) bf16_t Bs0[128 * 32];
  __shared__ alignas(16) bf16_t Bs1[128 * 32];

  const int tid = threadIdx.x;
  const int lane = tid & 63, wave = tid >> 6;
  const int quad = lane >> 4, l16 = lane & 15;
  const int wm = (wave >> 1) * 64;
  const int wn = (wave & 1) * 64;
  const int sr = tid >> 2;
  const int sc = (tid & 3) * 8;

  const int kEnd = (CAUSAL == 2) ? (((bm + 1) * 128 < K) ? (bm + 1) * 128 : K) : K;

  f32x4 acc[4][4] = {};

  const unsigned aOff = (unsigned)(rowBase + sr) * (unsigned)ldA + sc;
  const unsigned bOff = (unsigned)(bn * 128 + sr) * (unsigned)ldB + sc;
  const unsigned aOff2 = aOff + 64u * (unsigned)ldA;
  const unsigned bOff2 = bOff + 64u * (unsigned)ldB;
  const unsigned lOff = sr * 32 + sc;

  for (int k0 = 0; k0 < kEnd; k0 += 64) {
    async16(A + (aOff + k0), &As0[lOff]);
    async16(A + (aOff + k0 + 32), &As1[lOff]);
    async16(A + (aOff2 + k0), &As0[lOff + 64 * 32]);
    async16(A + (aOff2 + k0 + 32), &As1[lOff + 64 * 32]);
    async16(B + (bOff + k0), &Bs0[lOff]);
    async16(B + (bOff2 + k0), &Bs0[lOff + 64 * 32]);
    async16(B + (bOff + k0 + 32), &Bs1[lOff]);
    async16(B + (bOff2 + k0 + 32), &Bs1[lOff + 64 * 32]);
    __syncthreads();

    bf16x8 b0[4], b1[4];
#pragma unroll
    for (int j = 0; j < 4; ++j) {
      b0[j] = *(const bf16x8*)&Bs0[(wn + j * 16 + l16) * 32 + quad * 8];
      b1[j] = *(const bf16x8*)&Bs1[(wn + j * 16 + l16) * 32 + quad * 8];
    }
#pragma unroll
    for (int i = 0; i < 4; ++i) {
      const bf16x8 a0 = *(const bf16x8*)&As0[(wm + i * 16 + l16) * 32 + quad * 8];
      const bf16x8 a1 = *(const bf16x8*)&As1[(wm + i * 16 + l16) * 32 + quad * 8];
#pragma unroll
      for (int j = 0; j < 4; ++j) {
        acc[i][j] = __builtin_amdgcn_mfma_f32_16x16x32_bf16(a0, b0[j], acc[i][j], 0, 0, 0);
        acc[i][j] = __builtin_amdgcn_mfma_f32_16x16x32_bf16(a1, b1[j], acc[i][j], 0, 0, 0);
      }
    }
    __syncthreads();
  }

  if (OUT_MODE == 3) {
    // scores epilogue: exp + dropout-mask + per-row sum (no max subtraction:
    // scores ~ N(0,1) after scale, max over 8M ~ 6, exp sums < 1e6 -> fp32 ok)
    const bool mbf = (*flag != 0);
    float rp[4][4];
#pragma unroll
    for (int i = 0; i < 4; ++i)
#pragma unroll
      for (int r = 0; r < 4; ++r) rp[i][r] = 0.f;
#pragma unroll
    for (int i = 0; i < 4; ++i) {
      const int gr0 = rowBase + wm + i * 16 + quad * 4;
#pragma unroll
      for (int j = 0; j < 4; ++j) {
        const int gc = bn * 128 + wn + j * 16 + l16;
#pragma unroll
        for (int r = 0; r < 4; ++r) {
          const int grr = gr0 + r;
          float out = 0.f;
          if (gc <= grr) {
            const float e = __expf(acc[i][j][r] * scale);
            const size_t mIdx = (size_t)grr * S_DIM + gc;
            const float mk = mbf ? bf2f(((const unsigned short*)mask)[mIdx])
                                 : ((const float*)mask)[mIdx];
            out = e * mk;
            rp[i][r] += e;
          }
          ((unsigned short*)C)[(size_t)grr * ldC + gc] = f2bf(out);
        }
      }
    }
#pragma unroll
    for (int i = 0; i < 4; ++i) {
      const int gr0 = rowBase + wm + i * 16 + quad * 4;
#pragma unroll
      for (int r = 0; r < 4; ++r) {
        float p = rp[i][r];
        p += __shfl_xor(p, 1); p += __shfl_xor(p, 2);
        p += __shfl_xor(p, 4); p += __shfl_xor(p, 8);
        if (l16 == 0) atomicAdd(&rowsum[gr0 + r], p);
      }
    }
  } else {
    // av epilogue: normalize by softmax denominator, write d_out
    const bool obf = (*flag != 0);
#pragma unroll
    for (int i = 0; i < 4; ++i) {
      const int gr0 = rowBase + wm + i * 16 + quad * 4;
      float inv[4];
#pragma unroll
      for (int r = 0; r < 4; ++r) inv[r] = 1.0f / rowsum[gr0 + r];
#pragma unroll
      for (int j = 0; j < 4; ++j) {
        const int gc = bn * 128 + wn + j * 16 + l16;
#pragma unroll
        for (int r = 0; r < 4; ++r) {
          const float v = acc[i][j][r] * inv[r];
          const size_t idx = (size_t)(gr0 + r) * ldC + gc;
          if (obf) ((unsigned short*)C)[idx] = f2bf(v);
          else     ((float*)C)[idx] = v;
        }
      }
    }
  }
}

__global__ __launch_bounds__(256, 5)
void k_gemm_sc(const bf16_t* __restrict__ A, const bf16_t* __restrict__ B,
               void* __restrict__ C, int ldA, int ldB, int ldC, int K,
               float scale, const int* __restrict__ flag,
               const void* __restrict__ mask, float* __restrict__ rowsum) {
  gemm_body<3, 1>(A, B, C, ldA, ldB, ldC, K, scale, flag, mask, rowsum);
}
__global__ __launch_bounds__(256, 5)
void k_gemm_av(const bf16_t* __restrict__ A, const bf16_t* __restrict__ B,
               void* __restrict__ C, int ldA, int ldB, int ldC, int K,
               float scale, const int* __restrict__ flag,
               const void* __restrict__ mask, float* __restrict__ rowsum) {
  gemm_body<2, 2>(A, B, C, ldA, ldB, ldC, K, scale, flag, mask, rowsum);
}

// ---------------------------------------------------------------------------
// v-part of qkv [S, 6144] (cols 4096..6143) -> vT[D,S], bf16, 32x32 tiles
__global__ void k_transpose(const unsigned short* __restrict__ src, int ldS,
                            unsigned short* __restrict__ dst) {
  __shared__ unsigned short tile[32][33];
  const int bx = blockIdx.x * 32;
  const int by = blockIdx.y * 32;
  const int tx = threadIdx.x & 31, ty = threadIdx.x >> 5;
  for (int r = ty; r < 32; r += 8)
    tile[r][tx] = src[(size_t)(by + r) * ldS + bx + tx];
  __syncthreads();
  for (int r = ty; r < 32; r += 8)
    dst[(size_t)(bx + r) * S_DIM + by + tx] = tile[tx][r];
}

// ---------------------------------------------------------------------------
extern "C" void kernel_launch(void* const* d_in, const int* in_sizes, int n_in,
                              void* d_out, int out_size, void* d_ws, size_t ws_size,
                              hipStream_t stream) {
  const size_t MB = 1024ull * 1024ull;
  char* w = (char*)d_ws;
  int* flag = (int*)w;
  float* rowsum = (float*)(w + 256);                             // 16 KB
  char* base = w + 64 * 1024;
  unsigned short* xb   = (unsigned short*)(base);                // 16 MB
  unsigned short* wqkv = (unsigned short*)(base + 16 * MB);      // 24 MB (Wq|Wk|Wv)
  unsigned short* qkv  = (unsigned short*)(base + 40 * MB);      // 48 MB [S, 6144]
  unsigned short* vT   = (unsigned short*)(base + 88 * MB);      // 16 MB [D, S]
  // attn (32 MB) aliases xb + first 16MB of wqkv (dead after qkv GEMM)
  unsigned short* attn = (unsigned short*)(base);

  // prep: probe + x->bf16 (2M items) + W->bf16 (3M items) + rowsum + flag
  k_prep<<<(S_DIM * D_DIM / 4 + 3 * D_DIM * D_DIM / 4) / 256, 256, 0, stream>>>(
      d_in[0], d_in[1], d_in[2], d_in[3], xb, wqkv, flag, rowsum);

  // qkv = x @ [Wq;Wk;Wv]^T : [4096, 6144], 48x32 = 1536 blocks (m97-lite)
  k_gemm_qkv<<<dim3(6144 / 128, S_DIM / 128), dim3(256), 0, stream>>>(
      (const bf16_t*)xb, (const bf16_t*)wqkv, qkv, D_DIM, D_DIM, 6144, D_DIM);

  // vT[D, S] from v-part of qkv
  k_transpose<<<dim3(D_DIM / 32, S_DIM / 32), 256, 0, stream>>>(
      qkv + 4096, 6144, vT);

  // attn_unnorm = exp(q@k^T/sqrt(d)) * mask, 128x128 triangle tiles (528)
  k_gemm_sc<<<dim3(528), dim3(256), 0, stream>>>(
      (const bf16_t*)qkv, (const bf16_t*)(qkv + 2048), (void*)attn,
      6144, 6144, S_DIM, D_DIM, 0.022097086912079608f /* 1/sqrt(2048) */,
      flag, d_in[4], rowsum);

  // out = (attn_unnorm @ vT^T) / rowsum, 128-row tiles, kEnd=(bm+1)*128,
  // balanced remap (16 x 32 grid = 512 blocks)
  k_gemm_av<<<dim3(D_DIM / 128, 32), dim3(256), 0, stream>>>(
      (const bf16_t*)attn, (const bf16_t*)vT, d_out,
      S_DIM, S_DIM, D_DIM, S_DIM, 1.0f, flag, nullptr, rowsum);
}

// Round 10
// 453.876 us; speedup vs baseline: 1.1652x; 1.1652x over previous
//
#include <hip/hip_runtime.h>
#include <hip/hip_bf16.h>

typedef __bf16 bf16_t;
typedef __attribute__((ext_vector_type(8))) __bf16 bf16x8;
typedef __attribute__((ext_vector_type(4))) float f32x4;

#define S_DIM 4096
#define D_DIM 2048

__device__ __forceinline__ unsigned short f2bf(float f) {
  unsigned int u = __float_as_uint(f);
  u += 0x7fff + ((u >> 16) & 1);   // round-to-nearest-even
  return (unsigned short)(u >> 16);
}
__device__ __forceinline__ float bf2f(unsigned short h) {
  return __uint_as_float(((unsigned int)h) << 16);
}

// async global->LDS, 16B per lane. LDS dest must be wave-uniform base + lane*16.
__device__ __forceinline__ void async16(const void* g, void* l) {
  __builtin_amdgcn_global_load_lds(
      (const __attribute__((address_space(1))) void*)g,
      (__attribute__((address_space(3))) void*)l, 16, 0, 0);
}

// ---------------------------------------------------------------------------
// JOURNAL (rounds 0-9):
//  - R1 explicit LDS double-buffer: REGRESSED (m99/m100 reproduced).
//  - R2 TM=128 2-barrier everywhere: 427us. qkv 108us / MfmaUtil 42% = 954 TF
//    (m97-structure band). BANKED CONFIG.
//  - R3/R6/R7 deep-pipeline (T2-T5) ports: ALL REGRESSED (LDS-read ratio /
//    sched_barrier pinning / 1 blk-per-CU grid quantization, no TLP fallback).
//  - R8 launch-merge k_prep: NEUTRAL -> launch gaps are small under graph.
//  - R9 XCD swizzle + 5 blk/CU: BIG REGRESSION (529us; qkv FETCH 102->260MB).
//    With gridDim.x % 8 == 0 the DEFAULT round-robin already 2D-blocks each
//    XCD (same 6 bn-cols across ~6 bm-rows ~ 6MB ~ L2); chunked swizzle
//    linearized it into a 17MB stream -> L2 thrash. Check the default mapping
//    before remapping. REVERTED.
//  - R10: sc/av (2 blk/CU grids, drains 2x exposed vs qkv's 4-deep TLP) get
//    BK=128 (4x BK=32 subtiles, 64KB LDS): halves drain count at ZERO
//    occupancy cost (grids are already ~2/CU). qkv untouched (m132: BK=128
//    regresses when it costs co-residency).
// ---------------------------------------------------------------------------
// k_prep: dtype probe (per-block, no cross-block dep), x->bf16, W->bf16,
// rowsum zero, flag publish.
__global__ void k_prep(const void* __restrict__ x, const void* __restrict__ w0,
                       const void* __restrict__ w1, const void* __restrict__ w2,
                       unsigned short* __restrict__ xb,
                       unsigned short* __restrict__ wqkv,
                       int* __restrict__ flag, float* __restrict__ rowsum) {
  const int gid = blockIdx.x * 256 + threadIdx.x;
  __shared__ int cnt;
  if (threadIdx.x == 0) cnt = 0;
  __syncthreads();
  const unsigned int e = (((const unsigned int*)x)[threadIdx.x] >> 7) & 0xffu;
  if (e >= 100 && e <= 140) atomicAdd(&cnt, 1);
  __syncthreads();
  const bool isbf = (cnt > 128);
  if (gid == 0) *flag = isbf ? 1 : 0;
  if (gid < S_DIM) rowsum[gid] = 0.f;

  const int NX4 = S_DIM * D_DIM / 4;   // 2,097,152
  if (gid < NX4) {
    if (isbf) {
      ((uint2*)xb)[gid] = ((const uint2*)x)[gid];
    } else {
      float4 f = ((const float4*)x)[gid];
      ushort4 u;
      u.x = f2bf(f.x); u.y = f2bf(f.y); u.z = f2bf(f.z); u.w = f2bf(f.w);
      ((ushort4*)xb)[gid] = u;
    }
  } else {
    const int i = gid - NX4;           // 0 .. 3*1048576-1
    const int which = i >> 20;
    const int off = i & 0xFFFFF;
    const void* src = (which == 0) ? w0 : ((which == 1) ? w1 : w2);
    if (isbf) {
      ((uint2*)wqkv)[i] = ((const uint2*)src)[off];
    } else {
      float4 f = ((const float4*)src)[off];
      ushort4 u;
      u.x = f2bf(f.x); u.y = f2bf(f.y); u.z = f2bf(f.z); u.w = f2bf(f.w);
      ((ushort4*)wqkv)[i] = u;
    }
  }
}

// ===========================================================================
// m97-lite 2-barrier GEMM, 128x128 tile, 256 thr, waves 2x2, BK=64 as two
// BK=32 sub-tiles, 32KB LDS, 4 blocks/CU. PROVEN: qkv 108us / MfmaUtil 42%.
// Default blockIdx mapping (NO swizzle — see R9 journal).
__global__ __launch_bounds__(256, 4)
void k_gemm_qkv(const bf16_t* __restrict__ A, const bf16_t* __restrict__ B,
                unsigned short* __restrict__ C, int ldA, int ldB, int ldC, int K) {
  const int bm = blockIdx.y, bn = blockIdx.x;
  const int rowBase = bm * 128;

  __shared__ alignas(16) bf16_t As0[128 * 32];
  __shared__ alignas(16) bf16_t As1[128 * 32];
  __shared__ alignas(16) bf16_t Bs0[128 * 32];
  __shared__ alignas(16) bf16_t Bs1[128 * 32];

  const int tid = threadIdx.x;
  const int lane = tid & 63, wave = tid >> 6;
  const int quad = lane >> 4, l16 = lane & 15;
  const int wm = (wave >> 1) * 64;
  const int wn = (wave & 1) * 64;
  const int sr = tid >> 2;
  const int sc = (tid & 3) * 8;

  f32x4 acc[4][4] = {};

  const unsigned aOff = (unsigned)(rowBase + sr) * (unsigned)ldA + sc;
  const unsigned bOff = (unsigned)(bn * 128 + sr) * (unsigned)ldB + sc;
  const unsigned aOff2 = aOff + 64u * (unsigned)ldA;
  const unsigned bOff2 = bOff + 64u * (unsigned)ldB;
  const unsigned lOff = sr * 32 + sc;

  for (int k0 = 0; k0 < K; k0 += 64) {
    async16(A + (aOff + k0), &As0[lOff]);
    async16(A + (aOff + k0 + 32), &As1[lOff]);
    async16(A + (aOff2 + k0), &As0[lOff + 64 * 32]);
    async16(A + (aOff2 + k0 + 32), &As1[lOff + 64 * 32]);
    async16(B + (bOff + k0), &Bs0[lOff]);
    async16(B + (bOff2 + k0), &Bs0[lOff + 64 * 32]);
    async16(B + (bOff + k0 + 32), &Bs1[lOff]);
    async16(B + (bOff2 + k0 + 32), &Bs1[lOff + 64 * 32]);
    __syncthreads();

    bf16x8 b0[4], b1[4];
#pragma unroll
    for (int j = 0; j < 4; ++j) {
      b0[j] = *(const bf16x8*)&Bs0[(wn + j * 16 + l16) * 32 + quad * 8];
      b1[j] = *(const bf16x8*)&Bs1[(wn + j * 16 + l16) * 32 + quad * 8];
    }
#pragma unroll
    for (int i = 0; i < 4; ++i) {
      const bf16x8 a0 = *(const bf16x8*)&As0[(wm + i * 16 + l16) * 32 + quad * 8];
      const bf16x8 a1 = *(const bf16x8*)&As1[(wm + i * 16 + l16) * 32 + quad * 8];
#pragma unroll
      for (int j = 0; j < 4; ++j) {
        acc[i][j] = __builtin_amdgcn_mfma_f32_16x16x32_bf16(a0, b0[j], acc[i][j], 0, 0, 0);
        acc[i][j] = __builtin_amdgcn_mfma_f32_16x16x32_bf16(a1, b1[j], acc[i][j], 0, 0, 0);
      }
    }
    __syncthreads();
  }

#pragma unroll
  for (int i = 0; i < 4; ++i) {
    const int gr0 = rowBase + wm + i * 16 + quad * 4;
#pragma unroll
    for (int j = 0; j < 4; ++j) {
      const int gc = bn * 128 + wn + j * 16 + l16;
#pragma unroll
      for (int r = 0; r < 4; ++r)
        C[(size_t)(gr0 + r) * ldC + gc] = f2bf(acc[i][j][r]);
    }
  }
}

// ===========================================================================
// R10 sc/av body: 128x128 tile, BK = NSUB*32 (NSUB=4 -> 64KB LDS, 2 blk/CU —
// no occupancy cost since these grids are already ~2/CU; halves drain count).
// OUT_MODE: 2 = /rowsum then flag?bf16:f32 (av -> d_out)
//           3 = softmax-fused scores: exp*mask write + rowsum atomics
// CAUSAL:   1 = triangle 1-D grid over 128x128 tiles (528 blocks)
//           2 = causal-K truncation kEnd=(bm+1)*128 + balanced bm remap
template<int OUT_MODE, int CAUSAL, int NSUB>
__device__ __forceinline__ void gemm_body(
    const bf16_t* __restrict__ A, const bf16_t* __restrict__ B,
    void* __restrict__ C, int ldA, int ldB, int ldC, int K,
    float scale, const int* __restrict__ flag,
    const void* __restrict__ mask, float* __restrict__ rowsum) {
  int bm, bn;
  if (CAUSAL == 1) {
    const int t = blockIdx.x;
    int u = (int)((sqrtf(8.0f * (float)t + 1.0f) - 1.0f) * 0.5f);
    while (((u + 1) * (u + 2)) / 2 <= t) ++u;
    while ((u * (u + 1)) / 2 > t) --u;
    bm = u;
    bn = t - (u * (u + 1)) / 2;
  } else {
    const int gy = blockIdx.y;
    bm = (gy < 16) ? gy : (47 - gy);
    bn = blockIdx.x;
  }
  const int rowBase = bm * 128;

  __shared__ alignas(16) bf16_t As[NSUB][128 * 32];
  __shared__ alignas(16) bf16_t Bs[NSUB][128 * 32];

  const int tid = threadIdx.x;
  const int lane = tid & 63, wave = tid >> 6;
  const int quad = lane >> 4, l16 = lane & 15;
  const int wm = (wave >> 1) * 64;
  const int wn = (wave & 1) * 64;
  const int sr = tid >> 2;
  const int sc = (tid & 3) * 8;

  const int kEnd = (CAUSAL == 2) ? (((bm + 1) * 128 < K) ? (bm + 1) * 128 : K) : K;

  f32x4 acc[4][4] = {};

  const unsigned aOff = (unsigned)(rowBase + sr) * (unsigned)ldA + sc;
  const unsigned bOff = (unsigned)(bn * 128 + sr) * (unsigned)ldB + sc;
  const unsigned aOff2 = aOff + 64u * (unsigned)ldA;
  const unsigned bOff2 = bOff + 64u * (unsigned)ldB;
  const unsigned lOff = sr * 32 + sc;

  for (int k0 = 0; k0 < kEnd; k0 += NSUB * 32) {
#pragma unroll
    for (int s = 0; s < NSUB; ++s) {
      async16(A + (aOff + k0 + 32 * s), &As[s][lOff]);
      async16(A + (aOff2 + k0 + 32 * s), &As[s][lOff + 64 * 32]);
      async16(B + (bOff + k0 + 32 * s), &Bs[s][lOff]);
      async16(B + (bOff2 + k0 + 32 * s), &Bs[s][lOff + 64 * 32]);
    }
    __syncthreads();

#pragma unroll
    for (int s = 0; s < NSUB; ++s) {
      bf16x8 b[4];
#pragma unroll
      for (int j = 0; j < 4; ++j)
        b[j] = *(const bf16x8*)&Bs[s][(wn + j * 16 + l16) * 32 + quad * 8];
#pragma unroll
      for (int i = 0; i < 4; ++i) {
        const bf16x8 a = *(const bf16x8*)&As[s][(wm + i * 16 + l16) * 32 + quad * 8];
#pragma unroll
        for (int j = 0; j < 4; ++j)
          acc[i][j] = __builtin_amdgcn_mfma_f32_16x16x32_bf16(a, b[j], acc[i][j], 0, 0, 0);
      }
    }
    __syncthreads();
  }

  if (OUT_MODE == 3) {
    // scores epilogue: exp + dropout-mask + per-row sum (no max subtraction:
    // scores ~ N(0,1) after scale, max over 8M ~ 6, exp sums < 1e6 -> fp32 ok)
    const bool mbf = (*flag != 0);
    float rp[4][4];
#pragma unroll
    for (int i = 0; i < 4; ++i)
#pragma unroll
      for (int r = 0; r < 4; ++r) rp[i][r] = 0.f;
#pragma unroll
    for (int i = 0; i < 4; ++i) {
      const int gr0 = rowBase + wm + i * 16 + quad * 4;
#pragma unroll
      for (int j = 0; j < 4; ++j) {
        const int gc = bn * 128 + wn + j * 16 + l16;
#pragma unroll
        for (int r = 0; r < 4; ++r) {
          const int grr = gr0 + r;
          float out = 0.f;
          if (gc <= grr) {
            const float e = __expf(acc[i][j][r] * scale);
            const size_t mIdx = (size_t)grr * S_DIM + gc;
            const float mk = mbf ? bf2f(((const unsigned short*)mask)[mIdx])
                                 : ((const float*)mask)[mIdx];
            out = e * mk;
            rp[i][r] += e;
          }
          ((unsigned short*)C)[(size_t)grr * ldC + gc] = f2bf(out);
        }
      }
    }
#pragma unroll
    for (int i = 0; i < 4; ++i) {
      const int gr0 = rowBase + wm + i * 16 + quad * 4;
#pragma unroll
      for (int r = 0; r < 4; ++r) {
        float p = rp[i][r];
        p += __shfl_xor(p, 1); p += __shfl_xor(p, 2);
        p += __shfl_xor(p, 4); p += __shfl_xor(p, 8);
        if (l16 == 0) atomicAdd(&rowsum[gr0 + r], p);
      }
    }
  } else {
    // av epilogue: normalize by softmax denominator, write d_out
    const bool obf = (*flag != 0);
#pragma unroll
    for (int i = 0; i < 4; ++i) {
      const int gr0 = rowBase + wm + i * 16 + quad * 4;
      float inv[4];
#pragma unroll
      for (int r = 0; r < 4; ++r) inv[r] = 1.0f / rowsum[gr0 + r];
#pragma unroll
      for (int j = 0; j < 4; ++j) {
        const int gc = bn * 128 + wn + j * 16 + l16;
#pragma unroll
        for (int r = 0; r < 4; ++r) {
          const float v = acc[i][j][r] * inv[r];
          const size_t idx = (size_t)(gr0 + r) * ldC + gc;
          if (obf) ((unsigned short*)C)[idx] = f2bf(v);
          else     ((float*)C)[idx] = v;
        }
      }
    }
  }
}

__global__ __launch_bounds__(256, 2)
void k_gemm_sc(const bf16_t* __restrict__ A, const bf16_t* __restrict__ B,
               void* __restrict__ C, int ldA, int ldB, int ldC, int K,
               float scale, const int* __restrict__ flag,
               const void* __restrict__ mask, float* __restrict__ rowsum) {
  gemm_body<3, 1, 4>(A, B, C, ldA, ldB, ldC, K, scale, flag, mask, rowsum);
}
__global__ __launch_bounds__(256, 2)
void k_gemm_av(const bf16_t* __restrict__ A, const bf16_t* __restrict__ B,
               void* __restrict__ C, int ldA, int ldB, int ldC, int K,
               float scale, const int* __restrict__ flag,
               const void* __restrict__ mask, float* __restrict__ rowsum) {
  gemm_body<2, 2, 4>(A, B, C, ldA, ldB, ldC, K, scale, flag, mask, rowsum);
}

// ---------------------------------------------------------------------------
// v-part of qkv [S, 6144] (cols 4096..6143) -> vT[D,S], bf16, 32x32 tiles
__global__ void k_transpose(const unsigned short* __restrict__ src, int ldS,
                            unsigned short* __restrict__ dst) {
  __shared__ unsigned short tile[32][33];
  const int bx = blockIdx.x * 32;
  const int by = blockIdx.y * 32;
  const int tx = threadIdx.x & 31, ty = threadIdx.x >> 5;
  for (int r = ty; r < 32; r += 8)
    tile[r][tx] = src[(size_t)(by + r) * ldS + bx + tx];
  __syncthreads();
  for (int r = ty; r < 32; r += 8)
    dst[(size_t)(bx + r) * S_DIM + by + tx] = tile[tx][r];
}

// ---------------------------------------------------------------------------
extern "C" void kernel_launch(void* const* d_in, const int* in_sizes, int n_in,
                              void* d_out, int out_size, void* d_ws, size_t ws_size,
                              hipStream_t stream) {
  const size_t MB = 1024ull * 1024ull;
  char* w = (char*)d_ws;
  int* flag = (int*)w;
  float* rowsum = (float*)(w + 256);                             // 16 KB
  char* base = w + 64 * 1024;
  unsigned short* xb   = (unsigned short*)(base);                // 16 MB
  unsigned short* wqkv = (unsigned short*)(base + 16 * MB);      // 24 MB (Wq|Wk|Wv)
  unsigned short* qkv  = (unsigned short*)(base + 40 * MB);      // 48 MB [S, 6144]
  unsigned short* vT   = (unsigned short*)(base + 88 * MB);      // 16 MB [D, S]
  // attn (32 MB) aliases xb + first 16MB of wqkv (dead after qkv GEMM)
  unsigned short* attn = (unsigned short*)(base);

  // prep: probe + x->bf16 (2M items) + W->bf16 (3M items) + rowsum + flag
  k_prep<<<(S_DIM * D_DIM / 4 + 3 * D_DIM * D_DIM / 4) / 256, 256, 0, stream>>>(
      d_in[0], d_in[1], d_in[2], d_in[3], xb, wqkv, flag, rowsum);

  // qkv = x @ [Wq;Wk;Wv]^T : [4096, 6144], 48x32 = 1536 blocks (m97-lite)
  k_gemm_qkv<<<dim3(6144 / 128, S_DIM / 128), dim3(256), 0, stream>>>(
      (const bf16_t*)xb, (const bf16_t*)wqkv, qkv, D_DIM, D_DIM, 6144, D_DIM);

  // vT[D, S] from v-part of qkv
  k_transpose<<<dim3(D_DIM / 32, S_DIM / 32), 256, 0, stream>>>(
      qkv + 4096, 6144, vT);

  // attn_unnorm = exp(q@k^T/sqrt(d)) * mask, 128x128 triangle tiles (528),
  // BK=128 (R10)
  k_gemm_sc<<<dim3(528), dim3(256), 0, stream>>>(
      (const bf16_t*)qkv, (const bf16_t*)(qkv + 2048), (void*)attn,
      6144, 6144, S_DIM, D_DIM, 0.022097086912079608f /* 1/sqrt(2048) */,
      flag, d_in[4], rowsum);

  // out = (attn_unnorm @ vT^T) / rowsum, 128-row tiles, kEnd=(bm+1)*128,
  // balanced remap (16 x 32 grid = 512 blocks), BK=128 (R10)
  k_gemm_av<<<dim3(D_DIM / 128, 32), dim3(256), 0, stream>>>(
      (const bf16_t*)attn, (const bf16_t*)vT, d_out,
      S_DIM, S_DIM, D_DIM, S_DIM, 1.0f, flag, nullptr, rowsum);
}

// Round 11
// 407.730 us; speedup vs baseline: 1.2971x; 1.1132x over previous
//
#include <hip/hip_runtime.h>
#include <hip/hip_bf16.h>

typedef __bf16 bf16_t;
typedef __attribute__((ext_vector_type(8))) __bf16 bf16x8;
typedef __attribute__((ext_vector_type(4))) float f32x4;

#define S_DIM 4096
#define D_DIM 2048

__device__ __forceinline__ unsigned short f2bf(float f) {
  unsigned int u = __float_as_uint(f);
  u += 0x7fff + ((u >> 16) & 1);   // round-to-nearest-even
  return (unsigned short)(u >> 16);
}
__device__ __forceinline__ float bf2f(unsigned short h) {
  return __uint_as_float(((unsigned int)h) << 16);
}

// async global->LDS, 16B per lane. LDS dest must be wave-uniform base + lane*16.
__device__ __forceinline__ void async16(const void* g, void* l) {
  __builtin_amdgcn_global_load_lds(
      (const __attribute__((address_space(1))) void*)g,
      (__attribute__((address_space(3))) void*)l, 16, 0, 0);
}

// ---------------------------------------------------------------------------
// JOURNAL (rounds 0-10):
//  - R1 explicit LDS double-buffer: REGRESSED (m99/m100 reproduced).
//  - R2/R8 TM=128 2-barrier everywhere: 427-431us. qkv 108us / MfmaUtil 42%
//    = 954 TF (m97-structure band). BANKED CONFIG.
//  - R3/R6/R7 deep-pipeline (T2-T5) ports: ALL REGRESSED (LDS-read ratio /
//    sched_barrier pinning / 1 blk-per-CU grid quantization, no TLP fallback).
//  - R8 launch-merge k_prep: NEUTRAL -> launch gaps small under graph capture.
//  - R9 XCD swizzle + 5 blk/CU: BIG REGRESSION (529us; qkv FETCH 102->260MB).
//    Default round-robin already 2D-blocks each XCD when gridDim.x%8==0;
//    chunked swizzle turned a ~6MB L2 set into a 17MB stream. REVERTED.
//  - R10 sc/av BK=128 (64KB LDS): REGRESSED (sc 138us, occupancy 12.6% ~
//    1 blk/CU — LDS doubling DID cost co-residency; m132 applies). REVERTED.
//  - Conclusion: R2-body at 2 blk/CU is the local optimum for sc/av's
//    shape-capped grids (528/512 blocks). TLP is grid-limited, not tunable.
//  - R11: harvest clean overhead — fuse k_transpose into qkv epilogue
//    (v-blocks write vT directly via LDS transpose; deletes a kernel +
//    32MB HBM round-trip). sc/av/prep byte-identical to R8.
// ---------------------------------------------------------------------------
// k_prep: dtype probe (per-block, no cross-block dep), x->bf16, W->bf16,
// rowsum zero, flag publish.
__global__ void k_prep(const void* __restrict__ x, const void* __restrict__ w0,
                       const void* __restrict__ w1, const void* __restrict__ w2,
                       unsigned short* __restrict__ xb,
                       unsigned short* __restrict__ wqkv,
                       int* __restrict__ flag, float* __restrict__ rowsum) {
  const int gid = blockIdx.x * 256 + threadIdx.x;
  __shared__ int cnt;
  if (threadIdx.x == 0) cnt = 0;
  __syncthreads();
  const unsigned int e = (((const unsigned int*)x)[threadIdx.x] >> 7) & 0xffu;
  if (e >= 100 && e <= 140) atomicAdd(&cnt, 1);
  __syncthreads();
  const bool isbf = (cnt > 128);
  if (gid == 0) *flag = isbf ? 1 : 0;
  if (gid < S_DIM) rowsum[gid] = 0.f;

  const int NX4 = S_DIM * D_DIM / 4;   // 2,097,152
  if (gid < NX4) {
    if (isbf) {
      ((uint2*)xb)[gid] = ((const uint2*)x)[gid];
    } else {
      float4 f = ((const float4*)x)[gid];
      ushort4 u;
      u.x = f2bf(f.x); u.y = f2bf(f.y); u.z = f2bf(f.z); u.w = f2bf(f.w);
      ((ushort4*)xb)[gid] = u;
    }
  } else {
    const int i = gid - NX4;           // 0 .. 3*1048576-1
    const int which = i >> 20;
    const int off = i & 0xFFFFF;
    const void* src = (which == 0) ? w0 : ((which == 1) ? w1 : w2);
    if (isbf) {
      ((uint2*)wqkv)[i] = ((const uint2*)src)[off];
    } else {
      float4 f = ((const float4*)src)[off];
      ushort4 u;
      u.x = f2bf(f.x); u.y = f2bf(f.y); u.z = f2bf(f.z); u.w = f2bf(f.w);
      ((ushort4*)wqkv)[i] = u;
    }
  }
}

// ===========================================================================
// m97-lite 2-barrier GEMM, 128x128 tile, 256 thr, waves 2x2, BK=64 as two
// BK=32 sub-tiles, 32KB LDS, 4 blocks/CU. PROVEN: 108us / MfmaUtil 42%.
// R11: v-part blocks (bn>=32) write vT[D,S] directly (LDS transpose, pad-136
// layout: 272B row stride = 16B-multiple for aligned uint4 reads; coalesced
// 256B vT row segments). They skip the qkv-v write (nothing reads it: sc uses
// cols 0..4095 only). Non-v blocks unchanged.
__global__ __launch_bounds__(256, 4)
void k_gemm_qkv(const bf16_t* __restrict__ A, const bf16_t* __restrict__ B,
                unsigned short* __restrict__ C, unsigned short* __restrict__ vT,
                int ldA, int ldB, int ldC, int K) {
  const int bm = blockIdx.y, bn = blockIdx.x;
  const int rowBase = bm * 128;

  __shared__ alignas(16) bf16_t smem[16384];   // 32KB
  bf16_t* As0 = smem;
  bf16_t* As1 = smem + 4096;
  bf16_t* Bs0 = smem + 8192;
  bf16_t* Bs1 = smem + 12288;

  const int tid = threadIdx.x;
  const int lane = tid & 63, wave = tid >> 6;
  const int quad = lane >> 4, l16 = lane & 15;
  const int wm = (wave >> 1) * 64;
  const int wn = (wave & 1) * 64;
  const int sr = tid >> 2;
  const int sc = (tid & 3) * 8;

  f32x4 acc[4][4] = {};

  const unsigned aOff = (unsigned)(rowBase + sr) * (unsigned)ldA + sc;
  const unsigned bOff = (unsigned)(bn * 128 + sr) * (unsigned)ldB + sc;
  const unsigned aOff2 = aOff + 64u * (unsigned)ldA;
  const unsigned bOff2 = bOff + 64u * (unsigned)ldB;
  const unsigned lOff = sr * 32 + sc;

  for (int k0 = 0; k0 < K; k0 += 64) {
    async16(A + (aOff + k0), &As0[lOff]);
    async16(A + (aOff + k0 + 32), &As1[lOff]);
    async16(A + (aOff2 + k0), &As0[lOff + 64 * 32]);
    async16(A + (aOff2 + k0 + 32), &As1[lOff + 64 * 32]);
    async16(B + (bOff + k0), &Bs0[lOff]);
    async16(B + (bOff2 + k0), &Bs0[lOff + 64 * 32]);
    async16(B + (bOff + k0 + 32), &Bs1[lOff]);
    async16(B + (bOff2 + k0 + 32), &Bs1[lOff + 64 * 32]);
    __syncthreads();

    bf16x8 b0[4], b1[4];
#pragma unroll
    for (int j = 0; j < 4; ++j) {
      b0[j] = *(const bf16x8*)&Bs0[(wn + j * 16 + l16) * 32 + quad * 8];
      b1[j] = *(const bf16x8*)&Bs1[(wn + j * 16 + l16) * 32 + quad * 8];
    }
#pragma unroll
    for (int i = 0; i < 4; ++i) {
      const bf16x8 a0 = *(const bf16x8*)&As0[(wm + i * 16 + l16) * 32 + quad * 8];
      const bf16x8 a1 = *(const bf16x8*)&As1[(wm + i * 16 + l16) * 32 + quad * 8];
#pragma unroll
      for (int j = 0; j < 4; ++j) {
        acc[i][j] = __builtin_amdgcn_mfma_f32_16x16x32_bf16(a0, b0[j], acc[i][j], 0, 0, 0);
        acc[i][j] = __builtin_amdgcn_mfma_f32_16x16x32_bf16(a1, b1[j], acc[i][j], 0, 0, 0);
      }
    }
    __syncthreads();
  }

  if (bn < 32) {
    // q,k parts: plain bf16 write to qkv
#pragma unroll
    for (int i = 0; i < 4; ++i) {
      const int gr0 = rowBase + wm + i * 16 + quad * 4;
#pragma unroll
      for (int j = 0; j < 4; ++j) {
        const int gc = bn * 128 + wn + j * 16 + l16;
#pragma unroll
        for (int r = 0; r < 4; ++r)
          C[(size_t)(gr0 + r) * ldC + gc] = f2bf(acc[i][j][r]);
      }
    }
  } else {
    // v-part: transpose 128x128 tile through LDS, write vT[D,S] directly.
    // Per j-iter: 32 cols (16 at wn=0 half + 16 at wn=64 half) x 128 rows,
    // LDS layout [32][136] (pad 136 -> 272B stride, 16B-multiple).
    const int vbn = bn - 32;
    const int c_l = (wn >> 6) * 16 + l16;      // writer's local col 0..31
#pragma unroll
    for (int j = 0; j < 4; ++j) {
      __syncthreads();   // smem free (K-loop trailing barrier / prev j read)
#pragma unroll
      for (int i = 0; i < 4; ++i) {
        ushort4 p;
        p.x = f2bf(acc[i][j][0]); p.y = f2bf(acc[i][j][1]);
        p.z = f2bf(acc[i][j][2]); p.w = f2bf(acc[i][j][3]);
        *(ushort4*)&smem[c_l * 136 + wm + i * 16 + quad * 4] = p;
      }
      __syncthreads();
      // reader: thread t covers LDS col t>>3, seq chunk (t&7)*16 (16 bf16)
      const int c_l2 = tid >> 3;
      const int s0 = (tid & 7) * 16;
      const int c = (c_l2 < 16) ? (j * 16 + c_l2) : (64 + j * 16 + (c_l2 - 16));
      const uint4 lo = *(const uint4*)&smem[c_l2 * 136 + s0];
      const uint4 hi = *(const uint4*)&smem[c_l2 * 136 + s0 + 8];
      unsigned short* dst = &vT[(size_t)(vbn * 128 + c) * S_DIM + rowBase + s0];
      *(uint4*)dst = lo;
      *(uint4*)(dst + 8) = hi;
    }
  }
}

// ===========================================================================
// R2/R8 generic 2-barrier body for sc/av (banked config, byte-identical).
// OUT_MODE: 2 = /rowsum then flag?bf16:f32 (av -> d_out)
//           3 = softmax-fused scores: exp*mask write + rowsum atomics
// CAUSAL:   1 = triangle 1-D grid over 128x128 tiles (528 blocks)
//           2 = causal-K truncation kEnd=(bm+1)*128 + balanced bm remap
template<int OUT_MODE, int CAUSAL>
__device__ __forceinline__ void gemm_body(
    const bf16_t* __restrict__ A, const bf16_t* __restrict__ B,
    void* __restrict__ C, int ldA, int ldB, int ldC, int K,
    float scale, const int* __restrict__ flag,
    const void* __restrict__ mask, float* __restrict__ rowsum) {
  int bm, bn;
  if (CAUSAL == 1) {
    const int t = blockIdx.x;
    int u = (int)((sqrtf(8.0f * (float)t + 1.0f) - 1.0f) * 0.5f);
    while (((u + 1) * (u + 2)) / 2 <= t) ++u;
    while ((u * (u + 1)) / 2 > t) --u;
    bm = u;
    bn = t - (u * (u + 1)) / 2;
  } else {
    const int gy = blockIdx.y;
    bm = (gy < 16) ? gy : (47 - gy);
    bn = blockIdx.x;
  }
  const int rowBase = bm * 128;

  __shared__ alignas(16) bf16_t As0[128 * 32];
  __shared__ alignas(16) bf16_t As1[128 * 32];
  __shared__ alignas(16) bf16_t Bs0[128 * 32];
  __shared__ alignas(16) bf16_t Bs1[128 * 32];

  const int tid = threadIdx.x;
  const int lane = tid & 63, wave = tid >> 6;
  const int quad = lane >> 4, l16 = lane & 15;
  const int wm = (wave >> 1) * 64;
  const int wn = (wave & 1) * 64;
  const int sr = tid >> 2;
  const int sc = (tid & 3) * 8;

  const int kEnd = (CAUSAL == 2) ? (((bm + 1) * 128 < K) ? (bm + 1) * 128 : K) : K;

  f32x4 acc[4][4] = {};

  const unsigned aOff = (unsigned)(rowBase + sr) * (unsigned)ldA + sc;
  const unsigned bOff = (unsigned)(bn * 128 + sr) * (unsigned)ldB + sc;
  const unsigned aOff2 = aOff + 64u * (unsigned)ldA;
  const unsigned bOff2 = bOff + 64u * (unsigned)ldB;
  const unsigned lOff = sr * 32 + sc;

  for (int k0 = 0; k0 < kEnd; k0 += 64) {
    async16(A + (aOff + k0), &As0[lOff]);
    async16(A + (aOff + k0 + 32), &As1[lOff]);
    async16(A + (aOff2 + k0), &As0[lOff + 64 * 32]);
    async16(A + (aOff2 + k0 + 32), &As1[lOff + 64 * 32]);
    async16(B + (bOff + k0), &Bs0[lOff]);
    async16(B + (bOff2 + k0), &Bs0[lOff + 64 * 32]);
    async16(B + (bOff + k0 + 32), &Bs1[lOff]);
    async16(B + (bOff2 + k0 + 32), &Bs1[lOff + 64 * 32]);
    __syncthreads();

    bf16x8 b0[4], b1[4];
#pragma unroll
    for (int j = 0; j < 4; ++j) {
      b0[j] = *(const bf16x8*)&Bs0[(wn + j * 16 + l16) * 32 + quad * 8];
      b1[j] = *(const bf16x8*)&Bs1[(wn + j * 16 + l16) * 32 + quad * 8];
    }
#pragma unroll
    for (int i = 0; i < 4; ++i) {
      const bf16x8 a0 = *(const bf16x8*)&As0[(wm + i * 16 + l16) * 32 + quad * 8];
      const bf16x8 a1 = *(const bf16x8*)&As1[(wm + i * 16 + l16) * 32 + quad * 8];
#pragma unroll
      for (int j = 0; j < 4; ++j) {
        acc[i][j] = __builtin_amdgcn_mfma_f32_16x16x32_bf16(a0, b0[j], acc[i][j], 0, 0, 0);
        acc[i][j] = __builtin_amdgcn_mfma_f32_16x16x32_bf16(a1, b1[j], acc[i][j], 0, 0, 0);
      }
    }
    __syncthreads();
  }

  if (OUT_MODE == 3) {
    // scores epilogue: exp + dropout-mask + per-row sum (no max subtraction:
    // scores ~ N(0,1) after scale, max over 8M ~ 6, exp sums < 1e6 -> fp32 ok)
    const bool mbf = (*flag != 0);
    float rp[4][4];
#pragma unroll
    for (int i = 0; i < 4; ++i)
#pragma unroll
      for (int r = 0; r < 4; ++r) rp[i][r] = 0.f;
#pragma unroll
    for (int i = 0; i < 4; ++i) {
      const int gr0 = rowBase + wm + i * 16 + quad * 4;
#pragma unroll
      for (int j = 0; j < 4; ++j) {
        const int gc = bn * 128 + wn + j * 16 + l16;
#pragma unroll
        for (int r = 0; r < 4; ++r) {
          const int grr = gr0 + r;
          float out = 0.f;
          if (gc <= grr) {
            const float e = __expf(acc[i][j][r] * scale);
            const size_t mIdx = (size_t)grr * S_DIM + gc;
            const float mk = mbf ? bf2f(((const unsigned short*)mask)[mIdx])
                                 : ((const float*)mask)[mIdx];
            out = e * mk;
            rp[i][r] += e;
          }
          ((unsigned short*)C)[(size_t)grr * ldC + gc] = f2bf(out);
        }
      }
    }
#pragma unroll
    for (int i = 0; i < 4; ++i) {
      const int gr0 = rowBase + wm + i * 16 + quad * 4;
#pragma unroll
      for (int r = 0; r < 4; ++r) {
        float p = rp[i][r];
        p += __shfl_xor(p, 1); p += __shfl_xor(p, 2);
        p += __shfl_xor(p, 4); p += __shfl_xor(p, 8);
        if (l16 == 0) atomicAdd(&rowsum[gr0 + r], p);
      }
    }
  } else {
    // av epilogue: normalize by softmax denominator, write d_out
    const bool obf = (*flag != 0);
#pragma unroll
    for (int i = 0; i < 4; ++i) {
      const int gr0 = rowBase + wm + i * 16 + quad * 4;
      float inv[4];
#pragma unroll
      for (int r = 0; r < 4; ++r) inv[r] = 1.0f / rowsum[gr0 + r];
#pragma unroll
      for (int j = 0; j < 4; ++j) {
        const int gc = bn * 128 + wn + j * 16 + l16;
#pragma unroll
        for (int r = 0; r < 4; ++r) {
          const float v = acc[i][j][r] * inv[r];
          const size_t idx = (size_t)(gr0 + r) * ldC + gc;
          if (obf) ((unsigned short*)C)[idx] = f2bf(v);
          else     ((float*)C)[idx] = v;
        }
      }
    }
  }
}

__global__ __launch_bounds__(256, 4)
void k_gemm_sc(const bf16_t* __restrict__ A, const bf16_t* __restrict__ B,
               void* __restrict__ C, int ldA, int ldB, int ldC, int K,
               float scale, const int* __restrict__ flag,
               const void* __restrict__ mask, float* __restrict__ rowsum) {
  gemm_body<3, 1>(A, B, C, ldA, ldB, ldC, K, scale, flag, mask, rowsum);
}
__global__ __launch_bounds__(256, 4)
void k_gemm_av(const bf16_t* __restrict__ A, const bf16_t* __restrict__ B,
               void* __restrict__ C, int ldA, int ldB, int ldC, int K,
               float scale, const int* __restrict__ flag,
               const void* __restrict__ mask, float* __restrict__ rowsum) {
  gemm_body<2, 2>(A, B, C, ldA, ldB, ldC, K, scale, flag, mask, rowsum);
}

// ---------------------------------------------------------------------------
extern "C" void kernel_launch(void* const* d_in, const int* in_sizes, int n_in,
                              void* d_out, int out_size, void* d_ws, size_t ws_size,
                              hipStream_t stream) {
  const size_t MB = 1024ull * 1024ull;
  char* w = (char*)d_ws;
  int* flag = (int*)w;
  float* rowsum = (float*)(w + 256);                             // 16 KB
  char* base = w + 64 * 1024;
  unsigned short* xb   = (unsigned short*)(base);                // 16 MB
  unsigned short* wqkv = (unsigned short*)(base + 16 * MB);      // 24 MB (Wq|Wk|Wv)
  unsigned short* qkv  = (unsigned short*)(base + 40 * MB);      // 48 MB [S, 6144]
  unsigned short* vT   = (unsigned short*)(base + 88 * MB);      // 16 MB [D, S]
  // attn (32 MB) aliases xb + first 16MB of wqkv (dead after qkv GEMM)
  unsigned short* attn = (unsigned short*)(base);

  // prep: probe + x->bf16 (2M items) + W->bf16 (3M items) + rowsum + flag
  k_prep<<<(S_DIM * D_DIM / 4 + 3 * D_DIM * D_DIM / 4) / 256, 256, 0, stream>>>(
      d_in[0], d_in[1], d_in[2], d_in[3], xb, wqkv, flag, rowsum);

  // qkv = x @ [Wq;Wk;Wv]^T : [4096, 6144], 48x32 = 1536 blocks (m97-lite).
  // v-part blocks (bn>=32) write vT[D,S] directly (fused transpose, R11).
  k_gemm_qkv<<<dim3(6144 / 128, S_DIM / 128), dim3(256), 0, stream>>>(
      (const bf16_t*)xb, (const bf16_t*)wqkv, qkv, vT, D_DIM, D_DIM, 6144, D_DIM);

  // attn_unnorm = exp(q@k^T/sqrt(d)) * mask, 128x128 triangle tiles (528)
  k_gemm_sc<<<dim3(528), dim3(256), 0, stream>>>(
      (const bf16_t*)qkv, (const bf16_t*)(qkv + 2048), (void*)attn,
      6144, 6144, S_DIM, D_DIM, 0.022097086912079608f /* 1/sqrt(2048) */,
      flag, d_in[4], rowsum);

  // out = (attn_unnorm @ vT^T) / rowsum, 128-row tiles, kEnd=(bm+1)*128,
  // balanced remap (16 x 32 grid = 512 blocks)
  k_gemm_av<<<dim3(D_DIM / 128, 32), dim3(256), 0, stream>>>(
      (const bf16_t*)attn, (const bf16_t*)vT, d_out,
      S_DIM, S_DIM, D_DIM, S_DIM, 1.0f, flag, nullptr, rowsum);
}